// Round 2
// baseline (153.401 us; speedup 1.0000x reference)
//
#include <hip/hip_runtime.h>
#include <math.h>

#define BATCH 2048
#define SEQ 512
#define DIM 128

// ws layout: [0..127] qk (scaled), [128..131] qp (scaled), [132] c0 (scaled)
__global__ __launch_bounds__(128) void ap_prep(
    const float* __restrict__ query,
    const float* __restrict__ Wk, const float* __restrict__ bk,
    const float* __restrict__ Wp, const float* __restrict__ bp,
    float* __restrict__ ws)
{
    const float SCALE = 0.088388347648318447f;  // 128^-0.5
    const int d = threadIdx.x;
    // qk[d] = sum_k q[k] * Wk[k,d]   (coalesced across threads)
    float acc = 0.f;
    #pragma unroll 16
    for (int k = 0; k < DIM; ++k) acc += query[k] * Wk[k * DIM + d];
    ws[d] = acc * SCALE;
    if (d < 4) {
        float a = 0.f;
        for (int k = 0; k < DIM; ++k) a += query[k] * Wp[k * 4 + d];
        ws[DIM + d] = a * SCALE;
    }
    if (d == 0) {
        float c = 0.f;
        for (int k = 0; k < DIM; ++k) c += query[k] * (bk[k] + bp[k]);
        ws[DIM + 4] = c * SCALE;
    }
}

__global__ __launch_bounds__(256) void ap_main(
    const float* __restrict__ x, const float* __restrict__ pos,
    const int* __restrict__ mask,            // numpy bool -> harness int32
    const float* __restrict__ Wv, const float* __restrict__ bv,
    const float* __restrict__ ws, float* __restrict__ out)
{
    __shared__ float spos[SEQ];                    // per-row pos-score (+c0), masked
    __shared__ float sacc[8][DIM];                 // per-half-wave accumulators (rescaled)
    __shared__ float sm[8], sl[8];
    __shared__ alignas(16) float t[DIM];           // read back as float4

    const int b    = blockIdx.x;
    const int tid  = threadIdx.x;
    const int half = tid >> 5;        // 0..7 : which 32-lane group
    const int c    = tid & 31;        // column group (4 floats each)

    // broadcast score-vector pieces (tiny, L1/L2 resident)
    const float4 qk4 = ((const float4*)ws)[c];
    const float qp0 = ws[DIM + 0], qp1 = ws[DIM + 1];
    const float qp2 = ws[DIM + 2], qp3 = ws[DIM + 3];
    const float c0  = ws[DIM + 4];

    // positional part of the score for all 512 rows (coalesced float4 loads)
    for (int s = tid; s < SEQ; s += 256) {
        float4 p4 = ((const float4*)pos)[(size_t)b * SEQ + s];
        float sc = qp0 * p4.x + qp1 * p4.y + qp2 * p4.z + qp3 * p4.w + c0;
        if (mask[(size_t)b * SEQ + s] == 0) sc = -1e30f;
        spos[s] = sc;
    }
    __syncthreads();

    // ---- main streaming pass: each half-wave owns 64 rows, online softmax ----
    const float4* xb = (const float4*)(x + (size_t)b * SEQ * DIM);
    float m = -INFINITY, l = 0.f;
    float ax = 0.f, ay = 0.f, az = 0.f, aw = 0.f;
    const int row0 = half * 64;
    #pragma unroll 4
    for (int i = 0; i < 64; ++i) {
        const int s = row0 + i;
        float4 v = xb[s * 32 + c];                    // 512B coalesced per half-wave
        float r = qk4.x * v.x + qk4.y * v.y + qk4.z * v.z + qk4.w * v.w;
        r += __shfl_xor(r, 1);                        // 32-lane tree reduce
        r += __shfl_xor(r, 2);                        // (xor masks <32 stay in-half)
        r += __shfl_xor(r, 4);
        r += __shfl_xor(r, 8);
        r += __shfl_xor(r, 16);
        float sc = r + spos[s];
        float mn = fmaxf(m, sc);
        float f  = __expf(m - mn);
        float p  = __expf(sc - mn);
        l  = l  * f + p;
        ax = ax * f + p * v.x;
        ay = ay * f + p * v.y;
        az = az * f + p * v.z;
        aw = aw * f + p * v.w;
        m = mn;
    }

    // ---- merge the 8 half-wave online states ----
    if (c == 0) { sm[half] = m; sl[half] = l; }
    __syncthreads();
    float gm = fmaxf(fmaxf(fmaxf(sm[0], sm[1]), fmaxf(sm[2], sm[3])),
                     fmaxf(fmaxf(sm[4], sm[5]), fmaxf(sm[6], sm[7])));
    float f = __expf(m - gm);
    sacc[half][4 * c + 0] = ax * f;
    sacc[half][4 * c + 1] = ay * f;
    sacc[half][4 * c + 2] = az * f;
    sacc[half][4 * c + 3] = aw * f;
    float gl = 0.f;
    #pragma unroll
    for (int h = 0; h < 8; ++h) gl += sl[h] * __expf(sm[h] - gm);
    __syncthreads();

    if (tid < DIM) {
        float s0 = 0.f;
        #pragma unroll
        for (int h = 0; h < 8; ++h) s0 += sacc[h][tid];
        t[tid] = s0;
    }
    __syncthreads();

    // ---- epilogue: pooled[b,k] = bv[k] + (Wv[k,:] . t) / l ----
    if (tid < DIM) {
        const float4* wv4 = (const float4*)(Wv + tid * DIM);
        const float4* t4  = (const float4*)t;
        float sum = 0.f;
        #pragma unroll
        for (int j = 0; j < 32; ++j) {
            float4 w  = wv4[j];
            float4 tv = t4[j];                        // LDS broadcast
            sum += w.x * tv.x + w.y * tv.y + w.z * tv.z + w.w * tv.w;
        }
        out[(size_t)b * DIM + tid] = bv[tid] + sum / gl;
    }
}

extern "C" void kernel_launch(void* const* d_in, const int* in_sizes, int n_in,
                              void* d_out, int out_size, void* d_ws, size_t ws_size,
                              hipStream_t stream) {
    const float* x     = (const float*)d_in[0];
    const float* pos   = (const float*)d_in[1];
    const int*   mask  = (const int*)d_in[2];     // bool -> int32 per harness convention
    const float* query = (const float*)d_in[3];
    const float* Wk    = (const float*)d_in[4];
    const float* bk    = (const float*)d_in[5];
    const float* Wv    = (const float*)d_in[6];
    const float* bv    = (const float*)d_in[7];
    const float* Wp    = (const float*)d_in[8];
    const float* bp    = (const float*)d_in[9];
    float* out = (float*)d_out;
    float* ws  = (float*)d_ws;

    ap_prep<<<1, 128, 0, stream>>>(query, Wk, bk, Wp, bp, ws);
    ap_main<<<BATCH, 256, 0, stream>>>(x, pos, mask, Wv, bv, ws, out);
}

// Round 3
// 134.343 us; speedup vs baseline: 1.1419x; 1.1419x over previous
//
#include <hip/hip_runtime.h>
#include <math.h>

#define BATCH 2048
#define SEQ 512
#define DIM 128

// DPP rotate-within-16 add: after ror 1,2,4,8 every lane holds the 16-lane sum.
template<int CTRL>
__device__ __forceinline__ float dpp_add(float x) {
    int y = __builtin_amdgcn_update_dpp(0, __float_as_int(x), CTRL, 0xf, 0xf, true);
    return x + __int_as_float(y);
}

// ws layout: [0..127] qk (SCALE*log2e), [128..131] qp, [132] c0 — all exp2-prescaled
__global__ __launch_bounds__(256) void ap_prep(
    const float* __restrict__ query,
    const float* __restrict__ Wk, const float* __restrict__ bk,
    const float* __restrict__ Wp, const float* __restrict__ bp,
    float* __restrict__ ws)
{
    const float S2 = 0.08838834764831845f * 1.4426950408889634f;  // 128^-0.5 * log2(e)
    const int t = threadIdx.x;
    if (t < 128) {
        float acc = 0.f;
        #pragma unroll 16
        for (int k = 0; k < 128; ++k) acc += query[k] * Wk[k * 128 + t];
        ws[t] = acc * S2;
    } else if (t < 132) {
        const int d = t - 128;
        float a = 0.f;
        #pragma unroll 16
        for (int k = 0; k < 128; ++k) a += query[k] * Wp[k * 4 + d];
        ws[128 + d] = a * S2;
    } else if (t == 132) {
        float cc = 0.f;
        #pragma unroll 16
        for (int k = 0; k < 128; ++k) cc += query[k] * (bk[k] + bp[k]);
        ws[132] = cc * S2;
    }
}

__global__ __launch_bounds__(256) void ap_main(
    const float* __restrict__ x, const float* __restrict__ pos,
    const int* __restrict__ mask,
    const float* __restrict__ Wv, const float* __restrict__ bv,
    const float* __restrict__ ws, float* __restrict__ out)
{
    __shared__ float spos[520];                    // padded: idx = s + (s>>7)
    __shared__ float sacc[8][DIM];
    __shared__ float sm[8], sl[8];
    __shared__ alignas(16) float t[DIM];

    const int b   = blockIdx.x;
    const int tid = threadIdx.x;
    const int l   = tid & 63;
    const int w   = tid >> 6;         // wave 0..3, owns rows [128w, 128w+127]
    const int h   = (tid >> 5) & 1;   // half: even(0)/odd(1) rows of the wave
    const int c   = tid & 31;         // column group (4 floats)
    const int st  = tid >> 5;         // merge state 0..7

    const float4 qk4 = ((const float4*)ws)[c];
    const float qp0 = ws[128], qp1 = ws[129], qp2 = ws[130], qp3 = ws[131];
    const float c0  = ws[132];

    // positional score (+c0), exp2-prescaled, masked; bank-conflict-padded
    #pragma unroll
    for (int s = tid; s < SEQ; s += 256) {
        float4 p4 = ((const float4*)pos)[(size_t)b * SEQ + s];
        float sc = fmaf(qp0, p4.x, fmaf(qp1, p4.y, fmaf(qp2, p4.z, fmaf(qp3, p4.w, c0))));
        if (mask[(size_t)b * SEQ + s] == 0) sc = -1e30f;
        spos[s + (s >> 7)] = sc;
    }
    __syncthreads();

    // ---- streaming pass: contiguous 1KB per wave-load (rows 2i+h of wave w) ----
    const float4* xw = (const float4*)(x + (size_t)b * SEQ * DIM) + w * 4096;
    const int sp0 = w * 129 + h;      // padded spos index of row (128w + h)

    float m = -INFINITY, den = 0.f;
    float ax = 0.f, ay = 0.f, az = 0.f, aw = 0.f;

    float4 v = xw[l];                 // prefetch i=0
    #pragma unroll 4
    for (int i = 0; i < 64; ++i) {
        float4 vn = xw[((i + 1) & 63) * 64 + l];   // next row-pair (wraps: L1-hot, harmless)
        float r = v.x * qk4.x;
        r = fmaf(v.y, qk4.y, r);
        r = fmaf(v.z, qk4.z, r);
        r = fmaf(v.w, qk4.w, r);
        r = dpp_add<0x121>(r);        // row_ror:1
        r = dpp_add<0x122>(r);        // row_ror:2
        r = dpp_add<0x124>(r);        // row_ror:4
        r = dpp_add<0x128>(r);        // row_ror:8
        r += __shfl_xor(r, 16);       // combine the two 16-groups of this half
        float sc = r + spos[sp0 + 2 * i];
        float d  = sc - m;            // exp2 units
        if (__builtin_expect(d > 8.0f, 0)) {       // rare: new max beyond headroom
            float f = __builtin_amdgcn_exp2f(-d);  // d=+inf on first row -> f=0
            den = fmaf(den, f, 1.0f);
            ax = fmaf(ax, f, v.x); ay = fmaf(ay, f, v.y);
            az = fmaf(az, f, v.z); aw = fmaf(aw, f, v.w);
            m = sc;
        } else {                                    // common: no rescale
            float p = __builtin_amdgcn_exp2f(d);    // bounded by 2^8
            den += p;
            ax = fmaf(p, v.x, ax); ay = fmaf(p, v.y, ay);
            az = fmaf(p, v.z, az); aw = fmaf(p, v.w, aw);
        }
        v = vn;
    }

    // ---- merge the 8 states ----
    if (c == 0) { sm[st] = m; sl[st] = den; }
    __syncthreads();
    float gm = -INFINITY;
    #pragma unroll
    for (int k = 0; k < 8; ++k) gm = fmaxf(gm, sm[k]);
    float f = __builtin_amdgcn_exp2f(m - gm);
    sacc[st][4 * c + 0] = ax * f;
    sacc[st][4 * c + 1] = ay * f;
    sacc[st][4 * c + 2] = az * f;
    sacc[st][4 * c + 3] = aw * f;
    float gl = 0.f;
    #pragma unroll
    for (int k = 0; k < 8; ++k) gl += sl[k] * __builtin_amdgcn_exp2f(sm[k] - gm);
    __syncthreads();

    if (tid < DIM) {
        float s0 = 0.f;
        #pragma unroll
        for (int k = 0; k < 8; ++k) s0 += sacc[k][tid];
        t[tid] = s0;
    }
    __syncthreads();

    // ---- epilogue: pooled[b,k] = bv[k] + (Wv[k,:] . t) / gl ----
    if (tid < DIM) {
        const float4* wv4 = (const float4*)(Wv + tid * DIM);
        const float4* t4  = (const float4*)t;
        float sum = 0.f;
        #pragma unroll
        for (int j = 0; j < 32; ++j) {
            float4 wv = wv4[j];
            float4 tv = t4[j];
            sum += wv.x * tv.x + wv.y * tv.y + wv.z * tv.z + wv.w * tv.w;
        }
        out[(size_t)b * DIM + tid] = bv[tid] + sum / gl;
    }
}

extern "C" void kernel_launch(void* const* d_in, const int* in_sizes, int n_in,
                              void* d_out, int out_size, void* d_ws, size_t ws_size,
                              hipStream_t stream) {
    const float* x     = (const float*)d_in[0];
    const float* pos   = (const float*)d_in[1];
    const int*   mask  = (const int*)d_in[2];     // bool -> int32 per harness convention
    const float* query = (const float*)d_in[3];
    const float* Wk    = (const float*)d_in[4];
    const float* bk    = (const float*)d_in[5];
    const float* Wv    = (const float*)d_in[6];
    const float* bv    = (const float*)d_in[7];
    const float* Wp    = (const float*)d_in[8];
    const float* bp    = (const float*)d_in[9];
    float* out = (float*)d_out;
    float* ws  = (float*)d_ws;

    ap_prep<<<1, 256, 0, stream>>>(query, Wk, bk, Wp, bp, ws);
    ap_main<<<BATCH, 256, 0, stream>>>(x, pos, mask, Wv, bv, ws, out);
}

// Round 4
// 123.455 us; speedup vs baseline: 1.2426x; 1.0882x over previous
//
#include <hip/hip_runtime.h>
#include <math.h>

#define BATCH 2048
#define SEQ 512
#define DIM 128

// DPP rotate-within-16 add: after ror 1,2,4,8 every lane holds its 16-group sum.
template<int CTRL>
__device__ __forceinline__ float dpp_add(float x) {
    int y = __builtin_amdgcn_update_dpp(0, __float_as_int(x), CTRL, 0xf, 0xf, true);
    return x + __int_as_float(y);
}

// ws layout: [0..127] qk (SCALE*log2e), [128..131] qp, [132] c0 — all exp2-prescaled
__global__ __launch_bounds__(256) void ap_prep(
    const float* __restrict__ query,
    const float* __restrict__ Wk, const float* __restrict__ bk,
    const float* __restrict__ Wp, const float* __restrict__ bp,
    float* __restrict__ ws)
{
    const float S2 = 0.08838834764831845f * 1.4426950408889634f;  // 128^-0.5 * log2(e)
    const int t = threadIdx.x;
    if (t < 128) {
        float acc = 0.f;
        #pragma unroll 16
        for (int k = 0; k < 128; ++k) acc += query[k] * Wk[k * 128 + t];
        ws[t] = acc * S2;
    } else if (t < 132) {
        const int d = t - 128;
        float a = 0.f;
        #pragma unroll 16
        for (int k = 0; k < 128; ++k) a += query[k] * Wp[k * 4 + d];
        ws[128 + d] = a * S2;
    } else if (t == 132) {
        float cc = 0.f;
        #pragma unroll 16
        for (int k = 0; k < 128; ++k) cc += query[k] * (bk[k] + bp[k]);
        ws[132] = cc * S2;
    }
}

__global__ __launch_bounds__(256, 8) void ap_main(
    const float* __restrict__ x, const float* __restrict__ pos,
    const int* __restrict__ mask,
    const float* __restrict__ Wv, const float* __restrict__ bv,
    const float* __restrict__ ws, float* __restrict__ out)
{
    __shared__ float spos[520];                    // padded: idx = s + (s>>7)
    __shared__ float sacc[8][DIM];
    __shared__ float sm[8], sl[8];
    __shared__ alignas(16) float t[DIM];

    const int b   = blockIdx.x;
    const int tid = threadIdx.x;
    const int l   = tid & 63;
    const int w   = tid >> 6;         // wave 0..3, owns rows [128w, 128w+127]
    const int h   = (tid >> 5) & 1;   // half: even(0)/odd(1) rows of the wave
    const int c   = tid & 31;         // column group (4 floats)
    const int st  = tid >> 5;         // merge state 0..7

    // ---- issue first 4 x-loads immediately (hide spos phase under them) ----
    const float4* xw = (const float4*)(x + (size_t)b * SEQ * DIM) + w * 4096;
    float4 v0 = xw[0 * 64 + l];
    float4 v1 = xw[1 * 64 + l];
    float4 v2 = xw[2 * 64 + l];
    float4 v3 = xw[3 * 64 + l];

    const float4 qk4 = ((const float4*)ws)[c];
    const float qp0 = ws[128], qp1 = ws[129], qp2 = ws[130], qp3 = ws[131];
    const float c0  = ws[132];

    // positional score (+c0), exp2-prescaled, masked; bank-conflict-padded
    #pragma unroll
    for (int s = tid; s < SEQ; s += 256) {
        float4 p4 = ((const float4*)pos)[(size_t)b * SEQ + s];
        float sc = fmaf(qp0, p4.x, fmaf(qp1, p4.y, fmaf(qp2, p4.z, fmaf(qp3, p4.w, c0))));
        if (mask[(size_t)b * SEQ + s] == 0) sc = -1e30f;
        spos[s + (s >> 7)] = sc;
    }
    __syncthreads();

    const int sp0 = w * 129 + h;      // padded spos index of row (128w + h)

    float m = -INFINITY, den = 0.f;
    float ax = 0.f, ay = 0.f, az = 0.f, aw = 0.f;

#define PROC(V, J)                                                          \
    {                                                                       \
        float r = (V).x * qk4.x;                                            \
        r = fmaf((V).y, qk4.y, r);                                          \
        r = fmaf((V).z, qk4.z, r);                                          \
        r = fmaf((V).w, qk4.w, r);                                          \
        r = dpp_add<0x121>(r);                                              \
        r = dpp_add<0x122>(r);                                              \
        r = dpp_add<0x124>(r);                                              \
        r = dpp_add<0x128>(r);                                              \
        r += __shfl_xor(r, 16);                                             \
        float sc = r + spos[sp0 + 2 * (J)];                                 \
        float d  = sc - m;                                                  \
        if (__builtin_expect(d > 8.0f, 0)) {                                \
            float f = __builtin_amdgcn_exp2f(-d);                           \
            den = fmaf(den, f, 1.0f);                                       \
            ax = fmaf(ax, f, (V).x); ay = fmaf(ay, f, (V).y);               \
            az = fmaf(az, f, (V).z); aw = fmaf(aw, f, (V).w);               \
            m = sc;                                                         \
        } else {                                                            \
            float p = __builtin_amdgcn_exp2f(d);                            \
            den += p;                                                       \
            ax = fmaf(p, (V).x, ax); ay = fmaf(p, (V).y, ay);               \
            az = fmaf(p, (V).z, az); aw = fmaf(p, (V).w, aw);               \
        }                                                                   \
    }

    // ---- 4-deep rotating pipeline over 16 chunks (64 row-pairs) ----
    #pragma unroll
    for (int ch = 0; ch < 16; ++ch) {
        const int base = 4 * ch;
        PROC(v0, base + 0); v0 = xw[(((base + 4) & 63) * 64) + l];
        PROC(v1, base + 1); v1 = xw[(((base + 5) & 63) * 64) + l];
        PROC(v2, base + 2); v2 = xw[(((base + 6) & 63) * 64) + l];
        PROC(v3, base + 3); v3 = xw[(((base + 7) & 63) * 64) + l];
    }
#undef PROC

    // ---- merge the 8 states ----
    if (c == 0) { sm[st] = m; sl[st] = den; }
    __syncthreads();
    float gm = -INFINITY;
    #pragma unroll
    for (int k = 0; k < 8; ++k) gm = fmaxf(gm, sm[k]);
    float f = __builtin_amdgcn_exp2f(m - gm);
    sacc[st][4 * c + 0] = ax * f;
    sacc[st][4 * c + 1] = ay * f;
    sacc[st][4 * c + 2] = az * f;
    sacc[st][4 * c + 3] = aw * f;
    float gl = 0.f;
    #pragma unroll
    for (int k = 0; k < 8; ++k) gl += sl[k] * __builtin_amdgcn_exp2f(sm[k] - gm);
    __syncthreads();

    if (tid < DIM) {
        float s0 = 0.f;
        #pragma unroll
        for (int k = 0; k < 8; ++k) s0 += sacc[k][tid];
        t[tid] = s0;
    }
    __syncthreads();

    // ---- epilogue: pooled[b,k] = bv[k] + (Wv[k,:] . t) / gl ----
    if (tid < DIM) {
        const float4* wv4 = (const float4*)(Wv + tid * DIM);
        const float4* t4  = (const float4*)t;
        float sum = 0.f;
        #pragma unroll
        for (int j = 0; j < 32; ++j) {
            float4 wv = wv4[j];
            float4 tv = t4[j];
            sum += wv.x * tv.x + wv.y * tv.y + wv.z * tv.z + wv.w * tv.w;
        }
        out[(size_t)b * DIM + tid] = bv[tid] + sum / gl;
    }
}

extern "C" void kernel_launch(void* const* d_in, const int* in_sizes, int n_in,
                              void* d_out, int out_size, void* d_ws, size_t ws_size,
                              hipStream_t stream) {
    const float* x     = (const float*)d_in[0];
    const float* pos   = (const float*)d_in[1];
    const int*   mask  = (const int*)d_in[2];     // bool -> int32 per harness convention
    const float* query = (const float*)d_in[3];
    const float* Wk    = (const float*)d_in[4];
    const float* bk    = (const float*)d_in[5];
    const float* Wv    = (const float*)d_in[6];
    const float* bv    = (const float*)d_in[7];
    const float* Wp    = (const float*)d_in[8];
    const float* bp    = (const float*)d_in[9];
    float* out = (float*)d_out;
    float* ws  = (float*)d_ws;

    ap_prep<<<1, 256, 0, stream>>>(query, Wk, bk, Wp, bp, ws);
    ap_main<<<BATCH, 256, 0, stream>>>(x, pos, mask, Wv, bv, ws, out);
}